// Round 4
// baseline (671.314 us; speedup 1.0000x reference)
//
#include <hip/hip_runtime.h>
#include <hip/hip_fp16.h>

// ---------------------------------------------------------------------------
// GCN forward: 2x GCNConv(relu) + global_mean_pool + linear
// Strategy: device-built CSR (dst-grouped) reused across both layers;
// transform-first GEMMs (W in LDS) writing fp16; fp16 gather aggregation
// with fp32 accumulate; run-length pooling over sorted batch ids.
// R1: single-block scan (232us) -> 3-phase multi-block scan.
// R2: k_agg latency-bound -> multi-edge-group wave agg (171->123us).
// R3: agg at 48% HBM with 408MB fetch -> fp16 gathered operand (XW),
//     16B/lane half8 loads, NG=4/8 edge groups, depth-2 pipeline.
// ---------------------------------------------------------------------------

__global__ void k_init(int* __restrict__ cnt, float* __restrict__ psum,
                       float* __restrict__ pcnt, int n, int psumN, int G) {
  int i = blockIdx.x * 256 + threadIdx.x;
  if (i < n) cnt[i] = 0;
  if (i < psumN) psum[i] = 0.f;
  if (i < G) pcnt[i] = 0.f;
}

__global__ void k_count(const int* __restrict__ dst, int* __restrict__ cnt, int E) {
  int i = blockIdx.x * 256 + threadIdx.x;
  if (i < E) atomicAdd(&cnt[dst[i]], 1);
}

__global__ void k_dis(const int* __restrict__ cnt, float* __restrict__ dis, int n) {
  int i = blockIdx.x * 256 + threadIdx.x;
  if (i < n) dis[i] = rsqrtf((float)(cnt[i] + 1));  // +1 self-loop; deg>=1 always
}

// ---- 3-phase exclusive scan of cnt[0..n) -> rowptr, cursor ---------------
__global__ __launch_bounds__(256) void k_scanA(const int* __restrict__ cnt,
                                               int* __restrict__ bsum, int n) {
  __shared__ int red[256];
  int t = threadIdx.x;
  int base = blockIdx.x * 1024 + t * 4;
  int s = 0;
#pragma unroll
  for (int j = 0; j < 4; ++j) {
    int i = base + j;
    if (i < n) s += cnt[i];
  }
  red[t] = s;
  __syncthreads();
  for (int off = 128; off > 0; off >>= 1) {
    if (t < off) red[t] += red[t + off];
    __syncthreads();
  }
  if (t == 0) bsum[blockIdx.x] = red[0];
}

__global__ __launch_bounds__(256) void k_scanB(const int* __restrict__ bsum,
                                               int* __restrict__ boff, int NB) {
  __shared__ int sh[256];
  int t = threadIdx.x;
  sh[t] = (t < NB) ? bsum[t] : 0;
  __syncthreads();
  for (int off = 1; off < 256; off <<= 1) {
    int v = (t >= off) ? sh[t - off] : 0;
    __syncthreads();
    sh[t] += v;
    __syncthreads();
  }
  if (t < NB) boff[t] = (t == 0) ? 0 : sh[t - 1];
}

__global__ __launch_bounds__(256) void k_scanC(const int* __restrict__ cnt,
                                               const int* __restrict__ boff,
                                               int* __restrict__ rowptr,
                                               int* __restrict__ cursor, int n) {
  __shared__ int sh[256];
  int t = threadIdx.x;
  int base = blockIdx.x * 1024 + t * 4;
  int v[4];
  int s = 0;
#pragma unroll
  for (int j = 0; j < 4; ++j) {
    int i = base + j;
    v[j] = (i < n) ? cnt[i] : 0;
    s += v[j];
  }
  sh[t] = s;
  __syncthreads();
  for (int off = 1; off < 256; off <<= 1) {
    int u = (t >= off) ? sh[t - off] : 0;
    __syncthreads();
    sh[t] += u;
    __syncthreads();
  }
  int run = boff[blockIdx.x] + ((t == 0) ? 0 : sh[t - 1]);
#pragma unroll
  for (int j = 0; j < 4; ++j) {
    int i = base + j;
    if (i < n) {
      rowptr[i] = run;
      cursor[i] = run;
      run += v[j];
    }
  }
}

__global__ void k_build(const int* __restrict__ src, const int* __restrict__ dst,
                        const float* __restrict__ dis, int* __restrict__ cursor,
                        int* __restrict__ esrc, float* __restrict__ enorm, int E) {
  int i = blockIdx.x * 256 + threadIdx.x;
  if (i >= E) return;
  int s = src[i], d = dst[i];
  int slot = atomicAdd(&cursor[d], 1);
  esrc[slot] = s;
  enorm[slot] = dis[s] * dis[d];
}

// out[nrows, COLS] (fp16) = A[nrows, 128] (fp32) @ W[128, COLS]; W in LDS.
template <int COLS>
__global__ __launch_bounds__(256) void k_gemm(const float* __restrict__ A,
                                              const float* __restrict__ W,
                                              __half* __restrict__ out, int nrows) {
  __shared__ float Ws[128 * COLS];
  int t = threadIdx.x;
  for (int i = t * 4; i < 128 * COLS; i += 1024)
    *(float4*)&Ws[i] = *(const float4*)&W[i];
  __syncthreads();

  constexpr int CG = COLS / 4;   // col groups (32 or 16)
  constexpr int RG = 256 / CG;   // row groups (8 or 16)
  constexpr int RPT = 64 / RG;   // rows per thread (8 or 4)
  int tx = t % CG, ty = t / CG;
  int row0 = blockIdx.x * 64 + ty * RPT;
  int c0 = tx * 4;

  float acc[RPT][4];
#pragma unroll
  for (int r = 0; r < RPT; ++r)
    acc[r][0] = acc[r][1] = acc[r][2] = acc[r][3] = 0.f;

  bool full = (row0 + RPT <= nrows);
  for (int k = 0; k < 128; k += 4) {
    float4 w0 = *(const float4*)&Ws[(k + 0) * COLS + c0];
    float4 w1 = *(const float4*)&Ws[(k + 1) * COLS + c0];
    float4 w2 = *(const float4*)&Ws[(k + 2) * COLS + c0];
    float4 w3 = *(const float4*)&Ws[(k + 3) * COLS + c0];
#pragma unroll
    for (int r = 0; r < RPT; ++r) {
      int row = row0 + r;
      if (!full && row >= nrows) continue;
      float4 a = *(const float4*)&A[(size_t)row * 128 + k];
      acc[r][0] = fmaf(a.x, w0.x, acc[r][0]);
      acc[r][1] = fmaf(a.x, w0.y, acc[r][1]);
      acc[r][2] = fmaf(a.x, w0.z, acc[r][2]);
      acc[r][3] = fmaf(a.x, w0.w, acc[r][3]);
      acc[r][0] = fmaf(a.y, w1.x, acc[r][0]);
      acc[r][1] = fmaf(a.y, w1.y, acc[r][1]);
      acc[r][2] = fmaf(a.y, w1.z, acc[r][2]);
      acc[r][3] = fmaf(a.y, w1.w, acc[r][3]);
      acc[r][0] = fmaf(a.z, w2.x, acc[r][0]);
      acc[r][1] = fmaf(a.z, w2.y, acc[r][1]);
      acc[r][2] = fmaf(a.z, w2.z, acc[r][2]);
      acc[r][3] = fmaf(a.z, w2.w, acc[r][3]);
      acc[r][0] = fmaf(a.w, w3.x, acc[r][0]);
      acc[r][1] = fmaf(a.w, w3.y, acc[r][1]);
      acc[r][2] = fmaf(a.w, w3.z, acc[r][2]);
      acc[r][3] = fmaf(a.w, w3.w, acc[r][3]);
    }
  }
#pragma unroll
  for (int r = 0; r < RPT; ++r) {
    int row = row0 + r;
    if (full || row < nrows) {
      union { __half2 h2[2]; float2 f2; } u;
      u.h2[0] = __floats2half2_rn(acc[r][0], acc[r][1]);
      u.h2[1] = __floats2half2_rn(acc[r][2], acc[r][3]);
      *(float2*)&out[(size_t)row * COLS + c0] = u.f2;
    }
  }
}

// wave per node; COLS/8 lanes per edge-row (16B half8 loads), NG edge groups
// per wave, depth-2 pipeline. fp32 accumulate, fp32 output. Invalid: s=0,w=0.
template <int COLS>
__global__ __launch_bounds__(256) void k_agg(const __half* __restrict__ H,
                                             const int* __restrict__ rowptr,
                                             const int* __restrict__ rowend,
                                             const int* __restrict__ esrc,
                                             const float* __restrict__ enorm,
                                             const float* __restrict__ dis,
                                             const float* __restrict__ bias,
                                             float* __restrict__ out, int n) {
  constexpr int LPE = COLS / 8;  // lanes per edge-row (16 or 8)
  constexpr int NG = 64 / LPE;   // edge groups per wave (4 or 8)
  int node = (blockIdx.x * 256 + threadIdx.x) >> 6;
  if (node >= n) return;
  int lane = threadIdx.x & 63;
  int group = lane / LPE;
  int c = (lane % LPE) * 8;

  float acc[8];
#pragma unroll
  for (int j = 0; j < 8; ++j) acc[j] = 0.f;

  int beg = rowptr[node], end = rowend[node];
  int e0 = beg + group;
  int e1 = e0 + NG;
  int s0 = 0, s1 = 0;
  float w0 = 0.f, w1 = 0.f;
  if (e0 < end) { s0 = esrc[e0]; w0 = enorm[e0]; }
  if (e1 < end) { s1 = esrc[e1]; w1 = enorm[e1]; }
  while (e0 < end) {
    float4 r0 = *(const float4*)&H[(size_t)s0 * COLS + c];
    float4 r1 = *(const float4*)&H[(size_t)s1 * COLS + c];
    int e2 = e0 + 2 * NG, e3 = e1 + 2 * NG;
    int s2 = 0, s3 = 0;
    float w2 = 0.f, w3 = 0.f;
    if (e2 < end) { s2 = esrc[e2]; w2 = enorm[e2]; }
    if (e3 < end) { s3 = esrc[e3]; w3 = enorm[e3]; }
    {
      union { float4 f4; __half2 h2[4]; } u;
      u.f4 = r0;
#pragma unroll
      for (int j = 0; j < 4; ++j) {
        float2 f = __half22float2(u.h2[j]);
        acc[2 * j + 0] = fmaf(f.x, w0, acc[2 * j + 0]);
        acc[2 * j + 1] = fmaf(f.y, w0, acc[2 * j + 1]);
      }
      u.f4 = r1;
#pragma unroll
      for (int j = 0; j < 4; ++j) {
        float2 f = __half22float2(u.h2[j]);
        acc[2 * j + 0] = fmaf(f.x, w1, acc[2 * j + 0]);
        acc[2 * j + 1] = fmaf(f.y, w1, acc[2 * j + 1]);
      }
    }
    e0 = e2; s0 = s2; w0 = w2;
    e1 = e3; s1 = s3; w1 = w3;
  }
  // combine edge groups (lanes with equal lane%LPE)
#pragma unroll
  for (int m = LPE; m < 64; m <<= 1) {
#pragma unroll
    for (int j = 0; j < 8; ++j) acc[j] += __shfl_xor(acc[j], m, 64);
  }
  if (group == 0) {
    float dn = dis[node];
    float sw = dn * dn;
    union { float4 f4; __half2 h2[4]; } u;
    u.f4 = *(const float4*)&H[(size_t)node * COLS + c];
    float o[8];
#pragma unroll
    for (int j = 0; j < 4; ++j) {
      float2 f = __half22float2(u.h2[j]);
      o[2 * j + 0] = fmaxf(fmaf(f.x, sw, acc[2 * j + 0]) + bias[c + 2 * j + 0], 0.f);
      o[2 * j + 1] = fmaxf(fmaf(f.y, sw, acc[2 * j + 1]) + bias[c + 2 * j + 1], 0.f);
    }
    *(float4*)&out[(size_t)node * COLS + c] = make_float4(o[0], o[1], o[2], o[3]);
    *(float4*)&out[(size_t)node * COLS + c + 4] = make_float4(o[4], o[5], o[6], o[7]);
  }
}

// run-length pooling over sorted batch; 32 nodes per wave, lane = column
__global__ void k_pool(const float* __restrict__ H2, const int* __restrict__ batch,
                       float* __restrict__ psum, float* __restrict__ pcnt, int n) {
  int wv = (blockIdx.x * 256 + threadIdx.x) >> 6;
  int lane = threadIdx.x & 63;
  int start = wv * 32;
  if (start >= n) return;
  int end = min(start + 32, n);
  int curg = batch[start];
  float acc = 0.f;
  int cn = 0;
  for (int i = start; i < end; ++i) {
    int g = batch[i];
    if (g != curg) {
      atomicAdd(&psum[curg * 64 + lane], acc);
      if (lane == 0) atomicAdd(&pcnt[curg], (float)cn);
      acc = 0.f;
      cn = 0;
      curg = g;
    }
    acc += H2[(size_t)i * 64 + lane];
    ++cn;
  }
  atomicAdd(&psum[curg * 64 + lane], acc);
  if (lane == 0) atomicAdd(&pcnt[curg], (float)cn);
}

__global__ void k_final(const float* __restrict__ psum, const float* __restrict__ pcnt,
                        const float* __restrict__ lin_w, const float* __restrict__ lin_b,
                        float* __restrict__ out, int G) {
  int g = blockIdx.x * 64 + threadIdx.x;
  if (g >= G) return;
  float c = fmaxf(pcnt[g], 1.f);
  float s = 0.f;
  for (int i = 0; i < 64; ++i) s += psum[g * 64 + i] * lin_w[i];
  out[g] = s / c + lin_b[0];
}

extern "C" void kernel_launch(void* const* d_in, const int* in_sizes, int n_in,
                              void* d_out, int out_size, void* d_ws, size_t ws_size,
                              hipStream_t stream) {
  const float* x = (const float*)d_in[0];
  const int* edge = (const int*)d_in[1];
  const int* batch = (const int*)d_in[2];
  const float* W1 = (const float*)d_in[3];
  const float* b1 = (const float*)d_in[4];
  const float* W2 = (const float*)d_in[5];
  const float* b2 = (const float*)d_in[6];
  const float* lin_w = (const float*)d_in[7];
  const float* lin_b = (const float*)d_in[8];
  float* out = (float*)d_out;

  const int N = in_sizes[2];
  const int E = in_sizes[1] / 2;
  const int G = out_size;
  const int* esrc_in = edge;       // edge_index[0] = src
  const int* edst_in = edge + E;   // edge_index[1] = dst

  char* w = (char*)d_ws;
  size_t off = 0;
  auto take = [&](size_t bytes) {
    void* p = w + off;
    off += (bytes + 255) & ~(size_t)255;
    return p;
  };
  int* cnt = (int*)take((size_t)N * 4);
  int* rowptr = (int*)take((size_t)N * 4);
  int* cursor = (int*)take((size_t)N * 4);   // after build: cursor[i] == row end
  float* dis = (float*)take((size_t)N * 4);
  int* esrc = (int*)take((size_t)E * 4);
  float* enorm = (float*)take((size_t)E * 4);
  __half* XW = (__half*)take((size_t)N * 128 * 2);  // fp16; reused as [N,64] layer 2
  float* H1 = (float*)take((size_t)N * 128 * 4);    // fp32; reused as H2 [N,64]
  float* psum = (float*)take((size_t)G * 64 * 4);
  float* pcnt = (float*)take((size_t)G * 4);
  int* bsum = (int*)take(1024 * 4);
  int* boff = (int*)take(1024 * 4);
  (void)ws_size;
  (void)n_in;

  int nb_n = (N + 255) / 256;
  int nb_e = (E + 255) / 256;
  int NB = (N + 1023) / 1024;  // scan blocks (98 for N=100000; must be <= 256)

  k_init<<<nb_n, 256, 0, stream>>>(cnt, psum, pcnt, N, G * 64, G);
  k_count<<<nb_e, 256, 0, stream>>>(edst_in, cnt, E);
  k_dis<<<nb_n, 256, 0, stream>>>(cnt, dis, N);
  k_scanA<<<NB, 256, 0, stream>>>(cnt, bsum, N);
  k_scanB<<<1, 256, 0, stream>>>(bsum, boff, NB);
  k_scanC<<<NB, 256, 0, stream>>>(cnt, boff, rowptr, cursor, N);
  k_build<<<nb_e, 256, 0, stream>>>(esrc_in, edst_in, dis, cursor, esrc, enorm, E);

  int gb = (N + 63) / 64;
  int ab = (int)(((size_t)N * 64 + 255) / 256);

  // layer 1: XW = fp16(x@W1); H1 = relu(agg(XW) + b1) fp32
  k_gemm<128><<<gb, 256, 0, stream>>>(x, W1, XW, N);
  k_agg<128><<<ab, 256, 0, stream>>>(XW, rowptr, cursor, esrc, enorm, dis, b1, H1, N);

  // layer 2: XW[:, :64] = fp16(H1@W2); H2 (into H1 buffer) = relu(agg) + b2
  k_gemm<64><<<gb, 256, 0, stream>>>(H1, W2, XW, N);
  k_agg<64><<<ab, 256, 0, stream>>>(XW, rowptr, cursor, esrc, enorm, dis, b2, H1, N);

  // mean-pool + linear head
  int pb = (int)((((size_t)(N + 31) / 32) * 64 + 255) / 256);
  k_pool<<<pb, 256, 0, stream>>>(H1, batch, psum, pcnt, N);
  k_final<<<1, 64, 0, stream>>>(psum, pcnt, lin_w, lin_b, out, G);
}

// Round 5
// 485.836 us; speedup vs baseline: 1.3818x; 1.3818x over previous
//
#include <hip/hip_runtime.h>
#include <hip/hip_fp16.h>

// ---------------------------------------------------------------------------
// GCN forward: 2x GCNConv(relu) + global_mean_pool + linear
// Strategy: device-built CSR (dst-grouped) reused across both layers;
// transform-first GEMMs (W-column-tile in LDS) writing fp16; fp16 gather
// aggregation with fp32 accumulate; run-length pooling over sorted batch.
// R1: single-block scan (232us) -> 3-phase multi-block scan.
// R2: k_agg latency-bound -> multi-edge-group wave agg (171->123us).
// R3: agg 48% HBM, 408MB fetch -> fp16 gathered operand, 16B/lane loads.
// R4: gemm regressed (190us, 19% occ, branch-in-loop). -> 64x64 col-split
//     tiles (32KB LDS, 5 blocks/CU), branchless full path + separate tail.
// ---------------------------------------------------------------------------

__global__ void k_init(int* __restrict__ cnt, float* __restrict__ psum,
                       float* __restrict__ pcnt, int n, int psumN, int G) {
  int i = blockIdx.x * 256 + threadIdx.x;
  if (i < n) cnt[i] = 0;
  if (i < psumN) psum[i] = 0.f;
  if (i < G) pcnt[i] = 0.f;
}

__global__ void k_count(const int* __restrict__ dst, int* __restrict__ cnt, int E) {
  int i = blockIdx.x * 256 + threadIdx.x;
  if (i < E) atomicAdd(&cnt[dst[i]], 1);
}

__global__ void k_dis(const int* __restrict__ cnt, float* __restrict__ dis, int n) {
  int i = blockIdx.x * 256 + threadIdx.x;
  if (i < n) dis[i] = rsqrtf((float)(cnt[i] + 1));  // +1 self-loop; deg>=1 always
}

// ---- 3-phase exclusive scan of cnt[0..n) -> rowptr, cursor ---------------
__global__ __launch_bounds__(256) void k_scanA(const int* __restrict__ cnt,
                                               int* __restrict__ bsum, int n) {
  __shared__ int red[256];
  int t = threadIdx.x;
  int base = blockIdx.x * 1024 + t * 4;
  int s = 0;
#pragma unroll
  for (int j = 0; j < 4; ++j) {
    int i = base + j;
    if (i < n) s += cnt[i];
  }
  red[t] = s;
  __syncthreads();
  for (int off = 128; off > 0; off >>= 1) {
    if (t < off) red[t] += red[t + off];
    __syncthreads();
  }
  if (t == 0) bsum[blockIdx.x] = red[0];
}

__global__ __launch_bounds__(256) void k_scanB(const int* __restrict__ bsum,
                                               int* __restrict__ boff, int NB) {
  __shared__ int sh[256];
  int t = threadIdx.x;
  sh[t] = (t < NB) ? bsum[t] : 0;
  __syncthreads();
  for (int off = 1; off < 256; off <<= 1) {
    int v = (t >= off) ? sh[t - off] : 0;
    __syncthreads();
    sh[t] += v;
    __syncthreads();
  }
  if (t < NB) boff[t] = (t == 0) ? 0 : sh[t - 1];
}

__global__ __launch_bounds__(256) void k_scanC(const int* __restrict__ cnt,
                                               const int* __restrict__ boff,
                                               int* __restrict__ rowptr,
                                               int* __restrict__ cursor, int n) {
  __shared__ int sh[256];
  int t = threadIdx.x;
  int base = blockIdx.x * 1024 + t * 4;
  int v[4];
  int s = 0;
#pragma unroll
  for (int j = 0; j < 4; ++j) {
    int i = base + j;
    v[j] = (i < n) ? cnt[i] : 0;
    s += v[j];
  }
  sh[t] = s;
  __syncthreads();
  for (int off = 1; off < 256; off <<= 1) {
    int u = (t >= off) ? sh[t - off] : 0;
    __syncthreads();
    sh[t] += u;
    __syncthreads();
  }
  int run = boff[blockIdx.x] + ((t == 0) ? 0 : sh[t - 1]);
#pragma unroll
  for (int j = 0; j < 4; ++j) {
    int i = base + j;
    if (i < n) {
      rowptr[i] = run;
      cursor[i] = run;
      run += v[j];
    }
  }
}

__global__ void k_build(const int* __restrict__ src, const int* __restrict__ dst,
                        const float* __restrict__ dis, int* __restrict__ cursor,
                        int* __restrict__ esrc, float* __restrict__ enorm, int E) {
  int i = blockIdx.x * 256 + threadIdx.x;
  if (i >= E) return;
  int s = src[i], d = dst[i];
  int slot = atomicAdd(&cursor[d], 1);
  esrc[slot] = s;
  enorm[slot] = dis[s] * dis[d];
}

// out[nrows, COLS] (fp16) = A[nrows, 128] (fp32) @ W[128, COLS].
// Block = 64 rows x 64 cols; only this block's 64 W-columns staged in LDS
// (32KB -> 5 blocks/CU). 256 thr: 16 col-groups x 16 row-groups, 4 rows/thr.
template <int COLS>
__global__ __launch_bounds__(256) void k_gemm(const float* __restrict__ A,
                                              const float* __restrict__ W,
                                              __half* __restrict__ out, int nrows) {
  __shared__ float Ws[128 * 64];
  int t = threadIdx.x;
  int cbase = blockIdx.y * 64;
  // stage 64 columns of W: 128*64 floats, 256 threads * float4 -> 8 iters
  for (int i = t; i < 128 * 16; i += 256) {
    int k = i >> 4;
    int c = (i & 15) * 4;
    *(float4*)&Ws[k * 64 + c] = *(const float4*)&W[k * COLS + cbase + c];
  }
  __syncthreads();

  int tx = t & 15, ty = t >> 4;
  int row0 = blockIdx.x * 64 + ty * 4;
  int c0 = tx * 4;

  float acc[4][4];
#pragma unroll
  for (int r = 0; r < 4; ++r)
    acc[r][0] = acc[r][1] = acc[r][2] = acc[r][3] = 0.f;

  if (row0 + 4 <= nrows) {
    for (int k = 0; k < 128; k += 4) {
      float4 a0 = *(const float4*)&A[(size_t)(row0 + 0) * 128 + k];
      float4 a1 = *(const float4*)&A[(size_t)(row0 + 1) * 128 + k];
      float4 a2 = *(const float4*)&A[(size_t)(row0 + 2) * 128 + k];
      float4 a3 = *(const float4*)&A[(size_t)(row0 + 3) * 128 + k];
      float4 w0 = *(const float4*)&Ws[(k + 0) * 64 + c0];
      float4 w1 = *(const float4*)&Ws[(k + 1) * 64 + c0];
      float4 w2 = *(const float4*)&Ws[(k + 2) * 64 + c0];
      float4 w3 = *(const float4*)&Ws[(k + 3) * 64 + c0];
#define GEMM_FMA(r, a)                                  \
  acc[r][0] = fmaf(a.x, w0.x, acc[r][0]);               \
  acc[r][1] = fmaf(a.x, w0.y, acc[r][1]);               \
  acc[r][2] = fmaf(a.x, w0.z, acc[r][2]);               \
  acc[r][3] = fmaf(a.x, w0.w, acc[r][3]);               \
  acc[r][0] = fmaf(a.y, w1.x, acc[r][0]);               \
  acc[r][1] = fmaf(a.y, w1.y, acc[r][1]);               \
  acc[r][2] = fmaf(a.y, w1.z, acc[r][2]);               \
  acc[r][3] = fmaf(a.y, w1.w, acc[r][3]);               \
  acc[r][0] = fmaf(a.z, w2.x, acc[r][0]);               \
  acc[r][1] = fmaf(a.z, w2.y, acc[r][1]);               \
  acc[r][2] = fmaf(a.z, w2.z, acc[r][2]);               \
  acc[r][3] = fmaf(a.z, w2.w, acc[r][3]);               \
  acc[r][0] = fmaf(a.w, w3.x, acc[r][0]);               \
  acc[r][1] = fmaf(a.w, w3.y, acc[r][1]);               \
  acc[r][2] = fmaf(a.w, w3.z, acc[r][2]);               \
  acc[r][3] = fmaf(a.w, w3.w, acc[r][3]);
      GEMM_FMA(0, a0)
      GEMM_FMA(1, a1)
      GEMM_FMA(2, a2)
      GEMM_FMA(3, a3)
    }
#pragma unroll
    for (int r = 0; r < 4; ++r) {
      union { __half2 h2[2]; float2 f2; } u;
      u.h2[0] = __floats2half2_rn(acc[r][0], acc[r][1]);
      u.h2[1] = __floats2half2_rn(acc[r][2], acc[r][3]);
      *(float2*)&out[(size_t)(row0 + r) * COLS + cbase + c0] = u.f2;
    }
  } else {
    for (int k = 0; k < 128; k += 4) {
      float4 w0 = *(const float4*)&Ws[(k + 0) * 64 + c0];
      float4 w1 = *(const float4*)&Ws[(k + 1) * 64 + c0];
      float4 w2 = *(const float4*)&Ws[(k + 2) * 64 + c0];
      float4 w3 = *(const float4*)&Ws[(k + 3) * 64 + c0];
      for (int r = 0; r < 4; ++r) {
        int row = row0 + r;
        if (row >= nrows) continue;
        float4 a = *(const float4*)&A[(size_t)row * 128 + k];
        GEMM_FMA(r, a)
      }
    }
#pragma unroll
    for (int r = 0; r < 4; ++r) {
      int row = row0 + r;
      if (row < nrows) {
        union { __half2 h2[2]; float2 f2; } u;
        u.h2[0] = __floats2half2_rn(acc[r][0], acc[r][1]);
        u.h2[1] = __floats2half2_rn(acc[r][2], acc[r][3]);
        *(float2*)&out[(size_t)row * COLS + cbase + c0] = u.f2;
      }
    }
#undef GEMM_FMA
  }
}

// wave per node; COLS/8 lanes per edge-row (16B half8 loads), NG edge groups
// per wave, depth-2 pipeline. fp32 accumulate, fp32 output. Invalid: s=0,w=0.
template <int COLS>
__global__ __launch_bounds__(256) void k_agg(const __half* __restrict__ H,
                                             const int* __restrict__ rowptr,
                                             const int* __restrict__ rowend,
                                             const int* __restrict__ esrc,
                                             const float* __restrict__ enorm,
                                             const float* __restrict__ dis,
                                             const float* __restrict__ bias,
                                             float* __restrict__ out, int n) {
  constexpr int LPE = COLS / 8;  // lanes per edge-row (16 or 8)
  constexpr int NG = 64 / LPE;   // edge groups per wave (4 or 8)
  int node = (blockIdx.x * 256 + threadIdx.x) >> 6;
  if (node >= n) return;
  int lane = threadIdx.x & 63;
  int group = lane / LPE;
  int c = (lane % LPE) * 8;

  float acc[8];
#pragma unroll
  for (int j = 0; j < 8; ++j) acc[j] = 0.f;

  int beg = rowptr[node], end = rowend[node];
  int e0 = beg + group;
  int e1 = e0 + NG;
  int s0 = 0, s1 = 0;
  float w0 = 0.f, w1 = 0.f;
  if (e0 < end) { s0 = esrc[e0]; w0 = enorm[e0]; }
  if (e1 < end) { s1 = esrc[e1]; w1 = enorm[e1]; }
  while (e0 < end) {
    float4 r0 = *(const float4*)&H[(size_t)s0 * COLS + c];
    float4 r1 = *(const float4*)&H[(size_t)s1 * COLS + c];
    int e2 = e0 + 2 * NG, e3 = e1 + 2 * NG;
    int s2 = 0, s3 = 0;
    float w2 = 0.f, w3 = 0.f;
    if (e2 < end) { s2 = esrc[e2]; w2 = enorm[e2]; }
    if (e3 < end) { s3 = esrc[e3]; w3 = enorm[e3]; }
    {
      union { float4 f4; __half2 h2[4]; } u;
      u.f4 = r0;
#pragma unroll
      for (int j = 0; j < 4; ++j) {
        float2 f = __half22float2(u.h2[j]);
        acc[2 * j + 0] = fmaf(f.x, w0, acc[2 * j + 0]);
        acc[2 * j + 1] = fmaf(f.y, w0, acc[2 * j + 1]);
      }
      u.f4 = r1;
#pragma unroll
      for (int j = 0; j < 4; ++j) {
        float2 f = __half22float2(u.h2[j]);
        acc[2 * j + 0] = fmaf(f.x, w1, acc[2 * j + 0]);
        acc[2 * j + 1] = fmaf(f.y, w1, acc[2 * j + 1]);
      }
    }
    e0 = e2; s0 = s2; w0 = w2;
    e1 = e3; s1 = s3; w1 = w3;
  }
  // combine edge groups (lanes with equal lane%LPE)
#pragma unroll
  for (int m = LPE; m < 64; m <<= 1) {
#pragma unroll
    for (int j = 0; j < 8; ++j) acc[j] += __shfl_xor(acc[j], m, 64);
  }
  if (group == 0) {
    float dn = dis[node];
    float sw = dn * dn;
    union { float4 f4; __half2 h2[4]; } u;
    u.f4 = *(const float4*)&H[(size_t)node * COLS + c];
    float o[8];
#pragma unroll
    for (int j = 0; j < 4; ++j) {
      float2 f = __half22float2(u.h2[j]);
      o[2 * j + 0] = fmaxf(fmaf(f.x, sw, acc[2 * j + 0]) + bias[c + 2 * j + 0], 0.f);
      o[2 * j + 1] = fmaxf(fmaf(f.y, sw, acc[2 * j + 1]) + bias[c + 2 * j + 1], 0.f);
    }
    *(float4*)&out[(size_t)node * COLS + c] = make_float4(o[0], o[1], o[2], o[3]);
    *(float4*)&out[(size_t)node * COLS + c + 4] = make_float4(o[4], o[5], o[6], o[7]);
  }
}

// run-length pooling over sorted batch; 32 nodes per wave, lane = column
__global__ void k_pool(const float* __restrict__ H2, const int* __restrict__ batch,
                       float* __restrict__ psum, float* __restrict__ pcnt, int n) {
  int wv = (blockIdx.x * 256 + threadIdx.x) >> 6;
  int lane = threadIdx.x & 63;
  int start = wv * 32;
  if (start >= n) return;
  int end = min(start + 32, n);
  int curg = batch[start];
  float acc = 0.f;
  int cn = 0;
  for (int i = start; i < end; ++i) {
    int g = batch[i];
    if (g != curg) {
      atomicAdd(&psum[curg * 64 + lane], acc);
      if (lane == 0) atomicAdd(&pcnt[curg], (float)cn);
      acc = 0.f;
      cn = 0;
      curg = g;
    }
    acc += H2[(size_t)i * 64 + lane];
    ++cn;
  }
  atomicAdd(&psum[curg * 64 + lane], acc);
  if (lane == 0) atomicAdd(&pcnt[curg], (float)cn);
}

__global__ void k_final(const float* __restrict__ psum, const float* __restrict__ pcnt,
                        const float* __restrict__ lin_w, const float* __restrict__ lin_b,
                        float* __restrict__ out, int G) {
  int g = blockIdx.x * 64 + threadIdx.x;
  if (g >= G) return;
  float c = fmaxf(pcnt[g], 1.f);
  float s = 0.f;
  for (int i = 0; i < 64; ++i) s += psum[g * 64 + i] * lin_w[i];
  out[g] = s / c + lin_b[0];
}

extern "C" void kernel_launch(void* const* d_in, const int* in_sizes, int n_in,
                              void* d_out, int out_size, void* d_ws, size_t ws_size,
                              hipStream_t stream) {
  const float* x = (const float*)d_in[0];
  const int* edge = (const int*)d_in[1];
  const int* batch = (const int*)d_in[2];
  const float* W1 = (const float*)d_in[3];
  const float* b1 = (const float*)d_in[4];
  const float* W2 = (const float*)d_in[5];
  const float* b2 = (const float*)d_in[6];
  const float* lin_w = (const float*)d_in[7];
  const float* lin_b = (const float*)d_in[8];
  float* out = (float*)d_out;

  const int N = in_sizes[2];
  const int E = in_sizes[1] / 2;
  const int G = out_size;
  const int* esrc_in = edge;       // edge_index[0] = src
  const int* edst_in = edge + E;   // edge_index[1] = dst

  char* w = (char*)d_ws;
  size_t off = 0;
  auto take = [&](size_t bytes) {
    void* p = w + off;
    off += (bytes + 255) & ~(size_t)255;
    return p;
  };
  int* cnt = (int*)take((size_t)N * 4);
  int* rowptr = (int*)take((size_t)N * 4);
  int* cursor = (int*)take((size_t)N * 4);   // after build: cursor[i] == row end
  float* dis = (float*)take((size_t)N * 4);
  int* esrc = (int*)take((size_t)E * 4);
  float* enorm = (float*)take((size_t)E * 4);
  __half* XW = (__half*)take((size_t)N * 128 * 2);  // fp16; reused as [N,64] layer 2
  float* H1 = (float*)take((size_t)N * 128 * 4);    // fp32; reused as H2 [N,64]
  float* psum = (float*)take((size_t)G * 64 * 4);
  float* pcnt = (float*)take((size_t)G * 4);
  int* bsum = (int*)take(1024 * 4);
  int* boff = (int*)take(1024 * 4);
  (void)ws_size;
  (void)n_in;

  int nb_n = (N + 255) / 256;
  int nb_e = (E + 255) / 256;
  int NB = (N + 1023) / 1024;  // scan blocks (98 for N=100000; must be <= 256)

  k_init<<<nb_n, 256, 0, stream>>>(cnt, psum, pcnt, N, G * 64, G);
  k_count<<<nb_e, 256, 0, stream>>>(edst_in, cnt, E);
  k_dis<<<nb_n, 256, 0, stream>>>(cnt, dis, N);
  k_scanA<<<NB, 256, 0, stream>>>(cnt, bsum, N);
  k_scanB<<<1, 256, 0, stream>>>(bsum, boff, NB);
  k_scanC<<<NB, 256, 0, stream>>>(cnt, boff, rowptr, cursor, N);
  k_build<<<nb_e, 256, 0, stream>>>(esrc_in, edst_in, dis, cursor, esrc, enorm, E);

  int gb = (N + 63) / 64;
  int ab = (int)(((size_t)N * 64 + 255) / 256);

  // layer 1: XW = fp16(x@W1); H1 = relu(agg(XW) + b1) fp32
  k_gemm<128><<<dim3(gb, 2), 256, 0, stream>>>(x, W1, XW, N);
  k_agg<128><<<ab, 256, 0, stream>>>(XW, rowptr, cursor, esrc, enorm, dis, b1, H1, N);

  // layer 2: XW[:, :64] = fp16(H1@W2); H2 (into H1 buffer) = relu(agg) + b2
  k_gemm<64><<<dim3(gb, 1), 256, 0, stream>>>(H1, W2, XW, N);
  k_agg<64><<<ab, 256, 0, stream>>>(XW, rowptr, cursor, esrc, enorm, dis, b2, H1, N);

  // mean-pool + linear head
  int pb = (int)((((size_t)(N + 31) / 32) * 64 + 255) / 256);
  k_pool<<<pb, 256, 0, stream>>>(H1, batch, psum, pcnt, N);
  k_final<<<1, 64, 0, stream>>>(psum, pcnt, lin_w, lin_b, out, G);
}